// Round 1
// baseline (734.005 us; speedup 1.0000x reference)
//
#include <hip/hip_runtime.h>
#include <hip/hip_bf16.h>
#include <cstdint>

// Problem: B=32, S=2048, H=1024
//   h_proj[b,o] = sum_h hidden[b,h] * W_attn[o, h]            (Wh = W_attn[:, :H], indexed [o,h])
//   e_proj[b,s,o] = sum_h enc[b,s,h] * W_attn[o, H+h]         (We = W_attn[:, H:], indexed [o,h])
//   energy = tanh(e_proj + h_proj + b_attn)
//   attention[b,s] = sum_o energy[b,s,o] * v[o]
//   out = softmax(attention, axis=s)

#define HDIM 1024
#define BDIM 32
#define SDIM 2048

typedef __attribute__((ext_vector_type(8))) short short8;   // 8 bf16 (4 VGPRs)
typedef __attribute__((ext_vector_type(4))) float floatx4;  // MFMA accumulator

__device__ __forceinline__ unsigned short f2bf(float f) {
    // round-to-nearest-even fp32 -> bf16
    unsigned int u = __float_as_uint(f);
    u += 0x7fffu + ((u >> 16) & 1u);
    return (unsigned short)(u >> 16);
}

__device__ __forceinline__ float fast_tanh(float x) {
    // tanh(x) = 1 - 2/(e^{2x}+1); exp overflow -> inf -> 2/inf=0 -> 1 (correct limit)
    float e2 = __expf(2.f * x);
    return 1.f - 2.f * __builtin_amdgcn_rcpf(e2 + 1.f);
}

// ---- Kernel 1: convert We (W_attn[:, H:2H], row-major stride 2H) to bf16, K-contiguous ----
__global__ __launch_bounds__(256) void convert_B(const float* __restrict__ W,
                                                 unsigned short* __restrict__ Wbf) {
    int idx = (blockIdx.x * 256 + threadIdx.x) * 4;   // element index into (1024 x 1024)
    int o = idx >> 10;
    int h = idx & 1023;
    const float4 f = *(const float4*)(W + (size_t)o * 2048 + 1024 + h);
    ushort4 u;
    u.x = f2bf(f.x); u.y = f2bf(f.y); u.z = f2bf(f.z); u.w = f2bf(f.w);
    *(ushort4*)(Wbf + idx) = u;
}

// ---- Kernel 2: c[b,o] = sum_h hidden[b,h]*W_attn[o,h] + b_attn[o]  (fp32) ----
// one wave per o; lane-parallel over h; 32 accumulators (one per b)
__global__ __launch_bounds__(256) void calc_c(const float* __restrict__ hid,
                                              const float* __restrict__ W,
                                              const float* __restrict__ bias,
                                              float* __restrict__ c) {
    int wave = threadIdx.x >> 6;
    int lane = threadIdx.x & 63;
    int o = blockIdx.x * 4 + wave;   // grid 256 -> o in [0,1024)

    float acc[32];
#pragma unroll
    for (int b = 0; b < 32; ++b) acc[b] = 0.f;

    const float* wrow = W + (size_t)o * 2048;   // Wh[o, :]
    for (int k = lane; k < HDIM; k += 64) {
        float w = wrow[k];
#pragma unroll
        for (int b = 0; b < 32; ++b) acc[b] = fmaf(w, hid[b * HDIM + k], acc[b]);
    }
    float bo = bias[o];
#pragma unroll
    for (int b = 0; b < 32; ++b) {
        float x = acc[b];
        for (int off = 32; off; off >>= 1) x += __shfl_down(x, off);
        if (lane == 0) c[b * HDIM + o] = x + bo;
    }
}

// ---- Kernel 3: fused GEMM + tanh + v-dot ----
// 512 blocks, each owns 128 rows (one M-tile), loops over all 8 N-tiles of o.
// Per N-tile: full K loop with 16x16x32 bf16 MFMA; epilogue folds tanh(e+c)*v into
// per-row register accumulators. Single logits write per row (no atomics).
#define BM 128
#define BN 128
#define BK 32

__global__ __launch_bounds__(256) void attn_main(const float* __restrict__ enc,
                                                 const unsigned short* __restrict__ Wbf,
                                                 const float* __restrict__ c,
                                                 const float* __restrict__ v,
                                                 float* __restrict__ logits) {
    __shared__ __align__(16) unsigned short As[BM * BK];
    __shared__ __align__(16) unsigned short Bs[BN * BK];
    __shared__ float redbuf[2][BM];

    const int tid  = threadIdx.x;
    const int lane = tid & 63;
    const int wave = tid >> 6;
    const int wrow = (wave >> 1) * 64;
    const int wcol = (wave & 1) * 64;
    const int grp  = lane >> 4;     // 0..3
    const int lc   = lane & 15;     // 0..15

    const int m0 = blockIdx.x * BM;     // global row of this tile
    const int b  = m0 >> 11;            // m0 / 2048 (tiles never straddle b)

    // staging: each thread covers one half-row (16 elements) of the 128x32 tile
    const int st_row  = tid >> 1;            // 0..127
    const int st_half = (tid & 1) * 16;      // 0 or 16

    float rowsum[4][4];
#pragma unroll
    for (int i = 0; i < 4; ++i)
#pragma unroll
        for (int r = 0; r < 4; ++r) rowsum[i][r] = 0.f;

    const float*          a_base = enc + (size_t)(m0 + st_row) * HDIM + st_half;
    const int             koff   = grp * 8;

    for (int nt = 0; nt < 8; ++nt) {
        const int n0 = nt * BN;
        floatx4 acc[4][4];
#pragma unroll
        for (int i = 0; i < 4; ++i)
#pragma unroll
            for (int j = 0; j < 4; ++j) acc[i][j] = (floatx4){0.f, 0.f, 0.f, 0.f};

        const unsigned short* b_base = Wbf + (size_t)(n0 + st_row) * HDIM + st_half;

        for (int k0 = 0; k0 < HDIM; k0 += BK) {
            // ---- stage A (fp32 -> bf16) ----
            const float4* ap = (const float4*)(a_base + k0);
            float4 f0 = ap[0], f1 = ap[1], f2 = ap[2], f3 = ap[3];
            ushort4 u0, u1, u2, u3;
            u0.x = f2bf(f0.x); u0.y = f2bf(f0.y); u0.z = f2bf(f0.z); u0.w = f2bf(f0.w);
            u1.x = f2bf(f1.x); u1.y = f2bf(f1.y); u1.z = f2bf(f1.z); u1.w = f2bf(f1.w);
            u2.x = f2bf(f2.x); u2.y = f2bf(f2.y); u2.z = f2bf(f2.z); u2.w = f2bf(f2.w);
            u3.x = f2bf(f3.x); u3.y = f2bf(f3.y); u3.z = f2bf(f3.z); u3.w = f2bf(f3.w);
            ushort4* adst = (ushort4*)(As + st_row * BK + st_half);
            adst[0] = u0; adst[1] = u1; adst[2] = u2; adst[3] = u3;

            // ---- stage B (already bf16) ----
            const uint4* bp = (const uint4*)(b_base + k0);
            uint4* bdst = (uint4*)(Bs + st_row * BK + st_half);
            bdst[0] = bp[0]; bdst[1] = bp[1];

            __syncthreads();

            short8 af[4], bfr[4];
#pragma unroll
            for (int i = 0; i < 4; ++i)
                af[i] = *(const short8*)(As + (wrow + i * 16 + lc) * BK + koff);
#pragma unroll
            for (int j = 0; j < 4; ++j)
                bfr[j] = *(const short8*)(Bs + (wcol + j * 16 + lc) * BK + koff);

#pragma unroll
            for (int i = 0; i < 4; ++i)
#pragma unroll
                for (int j = 0; j < 4; ++j)
                    acc[i][j] = __builtin_amdgcn_mfma_f32_16x16x32_bf16(
                        af[i], bfr[j], acc[i][j], 0, 0, 0);

            __syncthreads();
        }

        // ---- epilogue for this N-tile: tanh(e + c) * v, accumulate per row ----
#pragma unroll
        for (int j = 0; j < 4; ++j) {
            const int n  = n0 + wcol + j * 16 + lc;
            const float vn = v[n];
            const float cv = c[b * HDIM + n];
#pragma unroll
            for (int i = 0; i < 4; ++i)
#pragma unroll
                for (int r = 0; r < 4; ++r) {
                    float e = acc[i][j][r] + cv;
                    rowsum[i][r] = fmaf(fast_tanh(e), vn, rowsum[i][r]);
                }
        }
    }

    // ---- reduce rowsum across the 16 lanes of each row-group, then across wcol waves ----
#pragma unroll
    for (int i = 0; i < 4; ++i)
#pragma unroll
        for (int r = 0; r < 4; ++r) {
            float x = rowsum[i][r];
            x += __shfl_xor(x, 8);
            x += __shfl_xor(x, 4);
            x += __shfl_xor(x, 2);
            x += __shfl_xor(x, 1);
            if (lc == 0) redbuf[wave & 1][wrow + i * 16 + grp * 4 + r] = x;
        }
    __syncthreads();
    if (tid < BM) logits[m0 + tid] = redbuf[0][tid] + redbuf[1][tid];
}

// ---- Kernel 4: softmax over S=2048 per batch row ----
__global__ __launch_bounds__(256) void softmax_k(const float* __restrict__ logits,
                                                 float* __restrict__ out) {
    __shared__ float wmax[4], wsum[4];
    const int bb = blockIdx.x;
    const int tid = threadIdx.x;
    const int wave = tid >> 6, lane = tid & 63;
    const float* lg = logits + (size_t)bb * SDIM;

    float vals[8];
    float lmax = -INFINITY;
#pragma unroll
    for (int q = 0; q < 8; ++q) {
        vals[q] = lg[q * 256 + tid];
        lmax = fmaxf(lmax, vals[q]);
    }
    for (int off = 32; off; off >>= 1) lmax = fmaxf(lmax, __shfl_xor(lmax, off));
    if (lane == 0) wmax[wave] = lmax;
    __syncthreads();
    lmax = fmaxf(fmaxf(wmax[0], wmax[1]), fmaxf(wmax[2], wmax[3]));

    float e[8];
    float s = 0.f;
#pragma unroll
    for (int q = 0; q < 8; ++q) {
        e[q] = __expf(vals[q] - lmax);
        s += e[q];
    }
    for (int off = 32; off; off >>= 1) s += __shfl_xor(s, off);
    if (lane == 0) wsum[wave] = s;
    __syncthreads();
    s = wsum[0] + wsum[1] + wsum[2] + wsum[3];
    const float inv = 1.f / s;
#pragma unroll
    for (int q = 0; q < 8; ++q)
        out[(size_t)bb * SDIM + q * 256 + tid] = e[q] * inv;
}

extern "C" void kernel_launch(void* const* d_in, const int* in_sizes, int n_in,
                              void* d_out, int out_size, void* d_ws, size_t ws_size,
                              hipStream_t stream) {
    const float* hidden = (const float*)d_in[0];   // (1, 32, 1024)
    const float* enc    = (const float*)d_in[1];   // (32, 2048, 1024)
    const float* W      = (const float*)d_in[2];   // (1024, 2048)
    const float* battn  = (const float*)d_in[3];   // (1024,)
    const float* v      = (const float*)d_in[4];   // (1024,)
    float* out = (float*)d_out;                    // (32, 2048)

    char* ws = (char*)d_ws;
    float* c            = (float*)ws;                           // 32*1024 fp32   = 128 KB
    float* logits       = (float*)(ws + (128 << 10));           // 65536 fp32     = 256 KB
    unsigned short* Wbf = (unsigned short*)(ws + (384 << 10));  // 1024*1024 bf16 = 2 MB

    hipLaunchKernelGGL(convert_B, dim3(1024), dim3(256), 0, stream, W, Wbf);
    hipLaunchKernelGGL(calc_c,    dim3(256),  dim3(256), 0, stream, hidden, W, battn, c);
    hipLaunchKernelGGL(attn_main, dim3(512),  dim3(256), 0, stream, enc, Wbf, c, v, logits);
    hipLaunchKernelGGL(softmax_k, dim3(32),   dim3(256), 0, stream, logits, out);
}

// Round 2
// 604.137 us; speedup vs baseline: 1.2150x; 1.2150x over previous
//
#include <hip/hip_runtime.h>
#include <hip/hip_bf16.h>
#include <cstdint>

// Problem: B=32, S=2048, H=1024
//   h_proj[b,o] = sum_h hidden[b,h] * W_attn[o, h]            (Wh = W_attn[:, :H])
//   e_proj[b,s,o] = sum_h enc[b,s,h] * W_attn[o, H+h]         (We = W_attn[:, H:])
//   energy = tanh(e_proj + h_proj + b_attn); attention[b,s] = energy . v
//   out = softmax(attention, axis=s)
//
// R2 structure: pre-convert enc & We to bf16; GEMM grid split over (mt,nt)=4096
// blocks writing per-nt partial logit sums; global_load_lds(16B) staging with
// XOR-swizzled LDS (global_load_lds forbids padding; swizzle kills the 8-way
// ds_read_b128 bank conflict measured in R1). Fallback to R1 path if ws small.

#define HDIM 1024
#define BDIM 32
#define SDIM 2048
#define MTOT (BDIM * SDIM)   // 65536 rows

typedef __attribute__((ext_vector_type(8))) short short8;   // 8 bf16 (4 VGPRs)
typedef __attribute__((ext_vector_type(4))) float floatx4;  // MFMA accumulator

__device__ __forceinline__ unsigned short f2bf(float f) {
    unsigned int u = __float_as_uint(f);
    u += 0x7fffu + ((u >> 16) & 1u);
    return (unsigned short)(u >> 16);
}
__device__ __forceinline__ unsigned int pack2(float a, float b) {
    return (unsigned int)f2bf(a) | ((unsigned int)f2bf(b) << 16);
}
__device__ __forceinline__ float fast_tanh(float x) {
    float e2 = __expf(2.f * x);
    return 1.f - 2.f * __builtin_amdgcn_rcpf(e2 + 1.f);
}
__device__ __forceinline__ void gload16(const void* g, void* l) {
    __builtin_amdgcn_global_load_lds(
        (const __attribute__((address_space(1))) unsigned int*)g,
        (__attribute__((address_space(3))) unsigned int*)l, 16, 0, 0);
}

// ---- convert We (W_attn[:, H:2H], row stride 2H) to bf16 K-contiguous ----
__global__ __launch_bounds__(256) void convert_W(const float* __restrict__ W,
                                                 unsigned short* __restrict__ Wbf) {
    int idx = (blockIdx.x * 256 + threadIdx.x) * 4;
    int o = idx >> 10;
    int h = idx & 1023;
    const float4 f = *(const float4*)(W + (size_t)o * 2048 + 1024 + h);
    ushort4 u;
    u.x = f2bf(f.x); u.y = f2bf(f.y); u.z = f2bf(f.z); u.w = f2bf(f.w);
    *(ushort4*)(Wbf + idx) = u;
}

// ---- convert enc (32,2048,1024) fp32 -> bf16, 16 elems/thread ----
__global__ __launch_bounds__(256) void convert_enc(const float* __restrict__ enc,
                                                   unsigned short* __restrict__ encbf) {
    size_t base = ((size_t)blockIdx.x * 256 + threadIdx.x) * 16;
    const float4* p = (const float4*)(enc + base);
    float4 a = p[0], b = p[1], c = p[2], d = p[3];
    uint4 o0, o1;
    o0.x = pack2(a.x, a.y); o0.y = pack2(a.z, a.w);
    o0.z = pack2(b.x, b.y); o0.w = pack2(b.z, b.w);
    o1.x = pack2(c.x, c.y); o1.y = pack2(c.z, c.w);
    o1.z = pack2(d.x, d.y); o1.w = pack2(d.z, d.w);
    uint4* q = (uint4*)(encbf + base);
    q[0] = o0; q[1] = o1;
}

// ---- c[b,o] = hidden[b,:] . Wh[o,:] + bias[o]; one block per o, waves split K ----
__global__ __launch_bounds__(256) void calc_c(const float* __restrict__ hid,
                                              const float* __restrict__ W,
                                              const float* __restrict__ bias,
                                              float* __restrict__ c) {
    __shared__ float red[4][32];
    const int o = blockIdx.x;
    const int wave = threadIdx.x >> 6, lane = threadIdx.x & 63;
    const int k = wave * 256 + lane * 4;
    const float4 wv = *(const float4*)(W + (size_t)o * 2048 + k);
    float acc[32];
#pragma unroll
    for (int b = 0; b < 32; ++b) {
        const float4 h = *(const float4*)(hid + b * HDIM + k);
        acc[b] = wv.x * h.x + wv.y * h.y + wv.z * h.z + wv.w * h.w;
    }
#pragma unroll
    for (int b = 0; b < 32; ++b) {
        float x = acc[b];
        for (int off = 32; off; off >>= 1) x += __shfl_xor(x, off);
        if (lane == 0) red[wave][b] = x;
    }
    __syncthreads();
    if (threadIdx.x < 32) {
        int b = threadIdx.x;
        c[b * HDIM + o] = red[0][b] + red[1][b] + red[2][b] + red[3][b] + bias[o];
    }
}

// ---- main fused GEMM+tanh+v-dot: one (mt,nt) 128x128 tile per block ----
#define BM 128
#define BN 128
#define BK 32

__global__ __launch_bounds__(256) void attn_mfma(const unsigned short* __restrict__ encbf,
                                                 const unsigned short* __restrict__ Wbf,
                                                 const float* __restrict__ c,
                                                 const float* __restrict__ v,
                                                 float* __restrict__ partials) {
    __shared__ __align__(16) unsigned short As[BM * BK];
    __shared__ __align__(16) unsigned short Bs[BN * BK];
    __shared__ float redbuf[2][BM];

    const int tid  = threadIdx.x;
    const int lane = tid & 63;
    const int wave = tid >> 6;
    const int wrow = (wave >> 1) * 64;
    const int wcol = (wave & 1) * 64;
    const int grp  = lane >> 4;
    const int lc   = lane & 15;

    const int mt = blockIdx.x >> 3;
    const int nt = blockIdx.x & 7;          // 8 adjacent blocks share one A-tile (L2/L3)
    const int m0 = mt * BM;
    const int n0 = nt * BN;
    const int b  = m0 >> 11;

    // global_load_lds staging: wave w issues 2x16 rows for A and B.
    // LDS slot s of row r holds global chunk c = s ^ ((r>>1)&3)  (chunk = 16B = 8 bf16)
    const int q0 = wave * 2, q1 = wave * 2 + 1;
    const int ch = (lane & 3) ^ ((lane >> 3) & 3);
    const int r0 = q0 * 16 + (lane >> 2);
    const int r1 = q1 * 16 + (lane >> 2);
    const unsigned short* gA0 = encbf + (size_t)(m0 + r0) * HDIM + ch * 8;
    const unsigned short* gA1 = encbf + (size_t)(m0 + r1) * HDIM + ch * 8;
    const unsigned short* gB0 = Wbf + (size_t)(n0 + r0) * HDIM + ch * 8;
    const unsigned short* gB1 = Wbf + (size_t)(n0 + r1) * HDIM + ch * 8;
    unsigned short* lA0 = As + q0 * 512;   // +lane*16B implicit
    unsigned short* lA1 = As + q1 * 512;
    unsigned short* lB0 = Bs + q0 * 512;
    unsigned short* lB1 = Bs + q1 * 512;

    // fragment-read swizzled k-offset (elements): slot = grp ^ ((lc>>1)&3)
    const int koff = (grp ^ ((lc >> 1) & 3)) * 8;

    floatx4 acc[4][4];
#pragma unroll
    for (int i = 0; i < 4; ++i)
#pragma unroll
        for (int j = 0; j < 4; ++j) acc[i][j] = (floatx4){0.f, 0.f, 0.f, 0.f};

    for (int k0 = 0; k0 < HDIM; k0 += BK) {
        gload16(gA0 + k0, lA0);
        gload16(gA1 + k0, lA1);
        gload16(gB0 + k0, lB0);
        gload16(gB1 + k0, lB1);
        __syncthreads();   // drains vmcnt -> LDS writes visible

        short8 af[4], bfr[4];
#pragma unroll
        for (int i = 0; i < 4; ++i)
            af[i] = *(const short8*)(As + (wrow + i * 16 + lc) * BK + koff);
#pragma unroll
        for (int j = 0; j < 4; ++j)
            bfr[j] = *(const short8*)(Bs + (wcol + j * 16 + lc) * BK + koff);

#pragma unroll
        for (int i = 0; i < 4; ++i)
#pragma unroll
            for (int j = 0; j < 4; ++j)
                acc[i][j] = __builtin_amdgcn_mfma_f32_16x16x32_bf16(
                    af[i], bfr[j], acc[i][j], 0, 0, 0);

        __syncthreads();   // protect LDS from next iteration's overwrite
    }

    // epilogue: rowsum[i][r] += tanh(acc + c[n]) * v[n] over this block's 128 n's
    float rowsum[4][4];
#pragma unroll
    for (int i = 0; i < 4; ++i)
#pragma unroll
        for (int r = 0; r < 4; ++r) rowsum[i][r] = 0.f;

#pragma unroll
    for (int j = 0; j < 4; ++j) {
        const int n  = n0 + wcol + j * 16 + lc;
        const float vn = v[n];
        const float cv = c[b * HDIM + n];
#pragma unroll
        for (int i = 0; i < 4; ++i)
#pragma unroll
            for (int r = 0; r < 4; ++r)
                rowsum[i][r] = fmaf(fast_tanh(acc[i][j][r] + cv), vn, rowsum[i][r]);
    }

#pragma unroll
    for (int i = 0; i < 4; ++i)
#pragma unroll
        for (int r = 0; r < 4; ++r) {
            float x = rowsum[i][r];
            x += __shfl_xor(x, 8);
            x += __shfl_xor(x, 4);
            x += __shfl_xor(x, 2);
            x += __shfl_xor(x, 1);
            if (lc == 0) redbuf[wave & 1][wrow + i * 16 + grp * 4 + r] = x;
        }
    __syncthreads();
    if (tid < BM) partials[(size_t)nt * MTOT + m0 + tid] = redbuf[0][tid] + redbuf[1][tid];
}

// ---- R1 fallback: nt-loop inside, fp32 in-loop convert (used only if ws too small) ----
__global__ __launch_bounds__(256) void attn_fallback(const float* __restrict__ enc,
                                                     const unsigned short* __restrict__ Wbf,
                                                     const float* __restrict__ c,
                                                     const float* __restrict__ v,
                                                     float* __restrict__ logits) {
    __shared__ __align__(16) unsigned short As[BM * BK];
    __shared__ __align__(16) unsigned short Bs[BN * BK];
    __shared__ float redbuf[2][BM];

    const int tid  = threadIdx.x;
    const int lane = tid & 63;
    const int wave = tid >> 6;
    const int wrow = (wave >> 1) * 64;
    const int wcol = (wave & 1) * 64;
    const int grp  = lane >> 4;
    const int lc   = lane & 15;
    const int m0 = blockIdx.x * BM;
    const int b  = m0 >> 11;
    const int st_row  = tid >> 1;
    const int st_half = (tid & 1) * 16;

    float rowsum[4][4];
#pragma unroll
    for (int i = 0; i < 4; ++i)
#pragma unroll
        for (int r = 0; r < 4; ++r) rowsum[i][r] = 0.f;

    const float* a_base = enc + (size_t)(m0 + st_row) * HDIM + st_half;
    const int koff = grp * 8;

    for (int nt = 0; nt < 8; ++nt) {
        const int n0 = nt * BN;
        floatx4 acc[4][4];
#pragma unroll
        for (int i = 0; i < 4; ++i)
#pragma unroll
            for (int j = 0; j < 4; ++j) acc[i][j] = (floatx4){0.f, 0.f, 0.f, 0.f};

        const unsigned short* b_base = Wbf + (size_t)(n0 + st_row) * HDIM + st_half;
        for (int k0 = 0; k0 < HDIM; k0 += BK) {
            const float4* ap = (const float4*)(a_base + k0);
            float4 f0 = ap[0], f1 = ap[1], f2 = ap[2], f3 = ap[3];
            ushort4 u0, u1, u2, u3;
            u0.x = f2bf(f0.x); u0.y = f2bf(f0.y); u0.z = f2bf(f0.z); u0.w = f2bf(f0.w);
            u1.x = f2bf(f1.x); u1.y = f2bf(f1.y); u1.z = f2bf(f1.z); u1.w = f2bf(f1.w);
            u2.x = f2bf(f2.x); u2.y = f2bf(f2.y); u2.z = f2bf(f2.z); u2.w = f2bf(f2.w);
            u3.x = f2bf(f3.x); u3.y = f2bf(f3.y); u3.z = f2bf(f3.z); u3.w = f2bf(f3.w);
            ushort4* adst = (ushort4*)(As + st_row * BK + st_half);
            adst[0] = u0; adst[1] = u1; adst[2] = u2; adst[3] = u3;
            const uint4* bp = (const uint4*)(b_base + k0);
            uint4* bdst = (uint4*)(Bs + st_row * BK + st_half);
            bdst[0] = bp[0]; bdst[1] = bp[1];
            __syncthreads();

            short8 af[4], bfr[4];
#pragma unroll
            for (int i = 0; i < 4; ++i)
                af[i] = *(const short8*)(As + (wrow + i * 16 + lc) * BK + koff);
#pragma unroll
            for (int j = 0; j < 4; ++j)
                bfr[j] = *(const short8*)(Bs + (wcol + j * 16 + lc) * BK + koff);
#pragma unroll
            for (int i = 0; i < 4; ++i)
#pragma unroll
                for (int j = 0; j < 4; ++j)
                    acc[i][j] = __builtin_amdgcn_mfma_f32_16x16x32_bf16(
                        af[i], bfr[j], acc[i][j], 0, 0, 0);
            __syncthreads();
        }
#pragma unroll
        for (int j = 0; j < 4; ++j) {
            const int n  = n0 + wcol + j * 16 + lc;
            const float vn = v[n];
            const float cv = c[b * HDIM + n];
#pragma unroll
            for (int i = 0; i < 4; ++i)
#pragma unroll
                for (int r = 0; r < 4; ++r)
                    rowsum[i][r] = fmaf(fast_tanh(acc[i][j][r] + cv), vn, rowsum[i][r]);
        }
    }
#pragma unroll
    for (int i = 0; i < 4; ++i)
#pragma unroll
        for (int r = 0; r < 4; ++r) {
            float x = rowsum[i][r];
            x += __shfl_xor(x, 8);
            x += __shfl_xor(x, 4);
            x += __shfl_xor(x, 2);
            x += __shfl_xor(x, 1);
            if (lc == 0) redbuf[wave & 1][wrow + i * 16 + grp * 4 + r] = x;
        }
    __syncthreads();
    if (tid < BM) logits[m0 + tid] = redbuf[0][tid] + redbuf[1][tid];
}

// ---- softmax over S=2048 per batch, summing npart partial logit slices ----
__global__ __launch_bounds__(256) void softmax_k(const float* __restrict__ partials,
                                                 float* __restrict__ out, int npart) {
    __shared__ float wred[4];
    const int bb = blockIdx.x;
    const int tid = threadIdx.x;
    const int wave = tid >> 6, lane = tid & 63;

    float vals[8];
    float lmax = -INFINITY;
#pragma unroll
    for (int q = 0; q < 8; ++q) {
        const size_t idx = (size_t)bb * SDIM + q * 256 + tid;
        float x = 0.f;
        for (int p = 0; p < npart; ++p) x += partials[(size_t)p * MTOT + idx];
        vals[q] = x;
        lmax = fmaxf(lmax, x);
    }
    for (int off = 32; off; off >>= 1) lmax = fmaxf(lmax, __shfl_xor(lmax, off));
    if (lane == 0) wred[wave] = lmax;
    __syncthreads();
    lmax = fmaxf(fmaxf(wred[0], wred[1]), fmaxf(wred[2], wred[3]));
    __syncthreads();

    float e[8];
    float s = 0.f;
#pragma unroll
    for (int q = 0; q < 8; ++q) {
        e[q] = __expf(vals[q] - lmax);
        s += e[q];
    }
    for (int off = 32; off; off >>= 1) s += __shfl_xor(s, off);
    if (lane == 0) wred[wave] = s;
    __syncthreads();
    s = wred[0] + wred[1] + wred[2] + wred[3];
    const float inv = 1.f / s;
#pragma unroll
    for (int q = 0; q < 8; ++q)
        out[(size_t)bb * SDIM + q * 256 + tid] = e[q] * inv;
}

extern "C" void kernel_launch(void* const* d_in, const int* in_sizes, int n_in,
                              void* d_out, int out_size, void* d_ws, size_t ws_size,
                              hipStream_t stream) {
    const float* hidden = (const float*)d_in[0];   // (1, 32, 1024)
    const float* enc    = (const float*)d_in[1];   // (32, 2048, 1024)
    const float* W      = (const float*)d_in[2];   // (1024, 2048)
    const float* battn  = (const float*)d_in[3];   // (1024,)
    const float* v      = (const float*)d_in[4];   // (1024,)
    float* out = (float*)d_out;                    // (32, 2048)

    char* ws = (char*)d_ws;
    const size_t off_c    = 0;                         // 128 KB
    const size_t off_part = 131072;                    // 8*65536*4 = 2 MB
    const size_t off_wbf  = off_part + 2097152;        // 2 MB
    const size_t off_enc  = off_wbf + 2097152;         // 128 MB
    const size_t need     = off_enc + (size_t)MTOT * HDIM * 2;

    float* c            = (float*)(ws + off_c);
    if (ws_size >= need) {
        float* partials     = (float*)(ws + off_part);
        unsigned short* Wbf = (unsigned short*)(ws + off_wbf);
        unsigned short* encbf = (unsigned short*)(ws + off_enc);
        hipLaunchKernelGGL(convert_W,   dim3(1024),  dim3(256), 0, stream, W, Wbf);
        hipLaunchKernelGGL(convert_enc, dim3(16384), dim3(256), 0, stream, enc, encbf);
        hipLaunchKernelGGL(calc_c,      dim3(1024),  dim3(256), 0, stream, hidden, W, battn, c);
        hipLaunchKernelGGL(attn_mfma,   dim3(4096),  dim3(256), 0, stream, encbf, Wbf, c, v, partials);
        hipLaunchKernelGGL(softmax_k,   dim3(32),    dim3(256), 0, stream, partials, out, 8);
    } else {
        // compact fallback layout (R1): c + 1 logits slice + Wbf = 2.43 MB
        float* logits       = (float*)(ws + 131072);           // 256 KB
        unsigned short* Wbf = (unsigned short*)(ws + 393216);  // 2 MB
        hipLaunchKernelGGL(convert_W, dim3(1024), dim3(256), 0, stream, W, Wbf);
        hipLaunchKernelGGL(calc_c,    dim3(1024), dim3(256), 0, stream, hidden, W, battn, c);
        hipLaunchKernelGGL(attn_fallback, dim3(512), dim3(256), 0, stream, enc, Wbf, c, v, logits);
        hipLaunchKernelGGL(softmax_k, dim3(32),   dim3(256), 0, stream, logits, out, 1);
    }
}

// Round 3
// 546.966 us; speedup vs baseline: 1.3420x; 1.1045x over previous
//
#include <hip/hip_runtime.h>
#include <hip/hip_bf16.h>
#include <cstdint>

// Problem: B=32, S=2048, H=1024
//   c[b,o]   = hidden[b,:].Wh[o,:] + bias[o]        (Wh = W_attn[:, :H])
//   e[b,s,o] = enc[b,s,:].We[o,:]                   (We = W_attn[:, H:])
//   logit[b,s] = sum_o tanh(e + c) * v[o];  out = softmax over s
//
// R3: single fused GEMM kernel, no 128 MB enc-bf16 intermediate.
//  - 1024 blocks x 512 threads, BM=64 rows/block, K pipelined in 8 phases of 128
//    through a 2x16KB double-buffered, XOR-swizzled bf16 LDS slab (one barrier/phase).
//  - B pre-packed fragment-major (convert_W2) so B-frags are coalesced 1KB global
//    loads from L2 (Wbf2 = 2 MB, L2-resident) -- no LDS, no barrier for B.
//  - per-wave partial logits -> softmax sums 8 slices (deterministic, no atomics).

#define HDIM 1024
#define SDIM 2048
#define MTOT 65536

typedef __attribute__((ext_vector_type(8))) short short8;   // 8 bf16
typedef __attribute__((ext_vector_type(4))) float floatx4;  // MFMA acc

__device__ __forceinline__ unsigned short f2bf(float f) {
    unsigned int u = __float_as_uint(f);
    u += 0x7fffu + ((u >> 16) & 1u);   // RNE
    return (unsigned short)(u >> 16);
}
__device__ __forceinline__ unsigned int pack2(float a, float b) {
    return (unsigned int)f2bf(a) | ((unsigned int)f2bf(b) << 16);
}
__device__ __forceinline__ float fast_tanh(float x) {
    float e2 = __expf(2.f * x);
    return 1.f - 2.f * __builtin_amdgcn_rcpf(e2 + 1.f);
}

// ---- convert We (W_attn[:, H:2H], row stride 2H) into fragment-major bf16 ----
// tile (jt in [0,64), kc in [0,32)): 16 n-rows x 32 k; ushort base = (jt*32+kc)*512.
// lane l = g*16+lc holds B[n=jt*16+lc][k=kc*32+g*8+jj], jj in [0,8) at base+l*8+jj.
__global__ __launch_bounds__(256) void convert_W2(const float* __restrict__ W,
                                                  unsigned short* __restrict__ Wbf2) {
    int T = blockIdx.x * 256 + threadIdx.x;   // [0, 131072): (n, k8)
    int n  = T >> 7;
    int k8 = T & 127;
    int k  = k8 * 8;
    const float4* src = (const float4*)(W + (size_t)n * 2048 + 1024 + k);
    float4 f0 = src[0], f1 = src[1];
    int jt = n >> 4, lc = n & 15, kc = k8 >> 2, g = k8 & 3;
    uint4 u;
    u.x = pack2(f0.x, f0.y); u.y = pack2(f0.z, f0.w);
    u.z = pack2(f1.x, f1.y); u.w = pack2(f1.z, f1.w);
    *(uint4*)(Wbf2 + (size_t)(jt * 32 + kc) * 512 + (g * 16 + lc) * 8) = u;
}

// ---- c[b,o] = hidden[b,:].Wh[o,:] + bias[o]; one block per o ----
__global__ __launch_bounds__(256) void calc_c(const float* __restrict__ hid,
                                              const float* __restrict__ W,
                                              const float* __restrict__ bias,
                                              float* __restrict__ c) {
    __shared__ float red[4][32];
    const int o = blockIdx.x;
    const int wave = threadIdx.x >> 6, lane = threadIdx.x & 63;
    const int k = wave * 256 + lane * 4;
    const float4 wv = *(const float4*)(W + (size_t)o * 2048 + k);
    float acc[32];
#pragma unroll
    for (int b = 0; b < 32; ++b) {
        const float4 h = *(const float4*)(hid + b * HDIM + k);
        acc[b] = wv.x * h.x + wv.y * h.y + wv.z * h.z + wv.w * h.w;
    }
#pragma unroll
    for (int b = 0; b < 32; ++b) {
        float x = acc[b];
        for (int off = 32; off; off >>= 1) x += __shfl_xor(x, off);
        if (lane == 0) red[wave][b] = x;
    }
    __syncthreads();
    if (threadIdx.x < 32) {
        int b = threadIdx.x;
        c[b * HDIM + o] = red[0][b] + red[1][b] + red[2][b] + red[3][b] + bias[o];
    }
}

// ---- fused GEMM + tanh + v-dot ----
#define PHN 8     // K phases
#define PHK 128   // K per phase

__global__ __launch_bounds__(512, 2) void attn_fused(const float* __restrict__ enc,
                                                     const unsigned short* __restrict__ Wbf2,
                                                     const float* __restrict__ c,
                                                     const float* __restrict__ v,
                                                     float* __restrict__ part) {
    // slab: 64 rows x 128 k bf16, row stride 128 ushorts; 16B chunk c16 of row r
    // stored at slot (c16 ^ (r&7)) -> frag reads are 2-way (free) bank aliasing.
    __shared__ __align__(16) unsigned short slab[2][64 * 128];   // 2 x 16 KB

    const int tid  = threadIdx.x;
    const int lane = tid & 63;
    const int wave = tid >> 6;    // 0..7
    const int grp  = lane >> 4;   // 0..3
    const int lc   = lane & 15;

    const int m0 = blockIdx.x * 64;
    const int b  = m0 >> 11;      // batch (64-row blocks never straddle b)

    // staging geometry: wave covers rows [wave*8, wave*8+8); q in [0,4):
    //   row = wave*8 + q*2 + (lane>>5),  kk = (lane&31)*4  (floats within 128-window)
    const int s_kk   = (lane & 31) * 4;
    const int s_rsub = lane >> 5;
    const int s_c16  = (lane & 31) >> 1;   // 16B chunk index of this lane's 4 floats
    const int s_b8   = lane & 1;           // low/high 8B of that chunk

    floatx4 acc[2][4][4];
#pragma unroll
    for (int cg = 0; cg < 2; ++cg)
#pragma unroll
        for (int i = 0; i < 4; ++i)
#pragma unroll
            for (int j = 0; j < 4; ++j) acc[cg][i][j] = (floatx4){0.f, 0.f, 0.f, 0.f};

    const short8* Bfr = (const short8*)Wbf2;   // tile*64 + lane indexing (16B units)

    float4 ld[4];
    // prologue: stage phase 0 into buf 0
#pragma unroll
    for (int q = 0; q < 4; ++q) {
        int row = wave * 8 + q * 2 + s_rsub;
        ld[q] = *(const float4*)(enc + (size_t)(m0 + row) * HDIM + s_kk);
    }
#pragma unroll
    for (int q = 0; q < 4; ++q) {
        int row  = wave * 8 + q * 2 + s_rsub;
        int slot = s_c16 ^ (row & 7);
        uint2 u = {pack2(ld[q].x, ld[q].y), pack2(ld[q].z, ld[q].w)};
        *(uint2*)(&slab[0][row * 128 + slot * 8 + s_b8 * 4]) = u;
    }

    // B lookahead ring: bf holds frags for flat step s (cg = s>>2, kc = s&3)
    short8 bf[4], bn[4];
#pragma unroll
    for (int j = 0; j < 4; ++j)
        bf[j] = Bfr[(size_t)((wave * 8 + 0 * 4 + j) * 32 + 0) * 64 + lane];

#pragma unroll 1
    for (int p = 0; p < PHN; ++p) {
        __syncthreads();   // slab[p&1] fully written

        if (p < PHN - 1) {
#pragma unroll
            for (int q = 0; q < 4; ++q) {
                int row = wave * 8 + q * 2 + s_rsub;
                ld[q] = *(const float4*)(enc + (size_t)(m0 + row) * HDIM +
                                         (p + 1) * PHK + s_kk);
            }
        }

        const unsigned short* sl = slab[p & 1];
#pragma unroll
        for (int s = 0; s < 8; ++s) {                 // cg = s>>2, kc = s&3
            const int cg = s >> 2, kc = s & 3;
            short8 af[4];
#pragma unroll
            for (int i = 0; i < 4; ++i) {
                int row  = i * 16 + lc;
                int slot = (kc * 4 + grp) ^ (lc & 7);
                af[i] = *(const short8*)(sl + row * 128 + slot * 16 / 2);
            }
            // prefetch B for step s+1 (crosses into next phase at s==7)
            {
                const int cg2 = (s < 7) ? ((s + 1) >> 2) : 0;
                const int kc2 = (s < 7) ? ((s + 1) & 3) : 0;
                const int pn  = (s < 7) ? p : ((p < PHN - 1) ? p + 1 : p);
#pragma unroll
                for (int j = 0; j < 4; ++j)
                    bn[j] = Bfr[(size_t)((wave * 8 + cg2 * 4 + j) * 32 +
                                         pn * 4 + kc2) * 64 + lane];
            }
#pragma unroll
            for (int i = 0; i < 4; ++i)
#pragma unroll
                for (int j = 0; j < 4; ++j)
                    acc[cg][i][j] = __builtin_amdgcn_mfma_f32_16x16x32_bf16(
                        af[i], bf[j], acc[cg][i][j], 0, 0, 0);
#pragma unroll
            for (int j = 0; j < 4; ++j) bf[j] = bn[j];
        }

        if (p < PHN - 1) {
#pragma unroll
            for (int q = 0; q < 4; ++q) {
                int row  = wave * 8 + q * 2 + s_rsub;
                int slot = s_c16 ^ (row & 7);
                uint2 u = {pack2(ld[q].x, ld[q].y), pack2(ld[q].z, ld[q].w)};
                *(uint2*)(&slab[(p + 1) & 1][row * 128 + slot * 8 + s_b8 * 4]) = u;
            }
        }
    }

    // epilogue: rowsum over this wave's 128 cols, tanh(e + c) * v
    float rowsum[4][4];
#pragma unroll
    for (int i = 0; i < 4; ++i)
#pragma unroll
        for (int r = 0; r < 4; ++r) rowsum[i][r] = 0.f;

#pragma unroll
    for (int cg = 0; cg < 2; ++cg)
#pragma unroll
        for (int j = 0; j < 4; ++j) {
            const int n  = wave * 128 + cg * 64 + j * 16 + lc;
            const float vn = v[n];
            const float cv = c[b * HDIM + n];
#pragma unroll
            for (int i = 0; i < 4; ++i)
#pragma unroll
                for (int r = 0; r < 4; ++r)
                    rowsum[i][r] = fmaf(fast_tanh(acc[cg][i][j][r] + cv), vn,
                                        rowsum[i][r]);
        }

#pragma unroll
    for (int i = 0; i < 4; ++i)
#pragma unroll
        for (int r = 0; r < 4; ++r) {
            float x = rowsum[i][r];
            x += __shfl_xor(x, 8);
            x += __shfl_xor(x, 4);
            x += __shfl_xor(x, 2);
            x += __shfl_xor(x, 1);
            if (lc == 0)
                part[(size_t)wave * MTOT + m0 + i * 16 + grp * 4 + r] = x;
        }
}

// ---- softmax over S=2048 per batch, summing npart partial logit slices ----
__global__ __launch_bounds__(256) void softmax_k(const float* __restrict__ partials,
                                                 float* __restrict__ out, int npart) {
    __shared__ float wred[4];
    const int bb = blockIdx.x;
    const int tid = threadIdx.x;
    const int wave = tid >> 6, lane = tid & 63;

    float vals[8];
    float lmax = -INFINITY;
#pragma unroll
    for (int q = 0; q < 8; ++q) {
        const size_t idx = (size_t)bb * SDIM + q * 256 + tid;
        float x = 0.f;
        for (int p = 0; p < npart; ++p) x += partials[(size_t)p * MTOT + idx];
        vals[q] = x;
        lmax = fmaxf(lmax, x);
    }
    for (int off = 32; off; off >>= 1) lmax = fmaxf(lmax, __shfl_xor(lmax, off));
    if (lane == 0) wred[wave] = lmax;
    __syncthreads();
    lmax = fmaxf(fmaxf(wred[0], wred[1]), fmaxf(wred[2], wred[3]));
    __syncthreads();

    float e[8];
    float s = 0.f;
#pragma unroll
    for (int q = 0; q < 8; ++q) {
        e[q] = __expf(vals[q] - lmax);
        s += e[q];
    }
    for (int off = 32; off; off >>= 1) s += __shfl_xor(s, off);
    if (lane == 0) wred[wave] = s;
    __syncthreads();
    s = wred[0] + wred[1] + wred[2] + wred[3];
    const float inv = 1.f / s;
#pragma unroll
    for (int q = 0; q < 8; ++q)
        out[(size_t)bb * SDIM + q * 256 + tid] = e[q] * inv;
}

extern "C" void kernel_launch(void* const* d_in, const int* in_sizes, int n_in,
                              void* d_out, int out_size, void* d_ws, size_t ws_size,
                              hipStream_t stream) {
    const float* hidden = (const float*)d_in[0];   // (1, 32, 1024)
    const float* enc    = (const float*)d_in[1];   // (32, 2048, 1024)
    const float* W      = (const float*)d_in[2];   // (1024, 2048)
    const float* battn  = (const float*)d_in[3];   // (1024,)
    const float* v      = (const float*)d_in[4];   // (1024,)
    float* out = (float*)d_out;                    // (32, 2048)

    char* ws = (char*)d_ws;
    float* c             = (float*)ws;                          // 128 KB
    float* part          = (float*)(ws + (128 << 10));          // 8*65536*4 = 2 MB
    unsigned short* Wbf2 = (unsigned short*)(ws + (128 << 10) + (2 << 20));  // 2 MB

    hipLaunchKernelGGL(convert_W2, dim3(512),  dim3(256), 0, stream, W, Wbf2);
    hipLaunchKernelGGL(calc_c,     dim3(1024), dim3(256), 0, stream, hidden, W, battn, c);
    hipLaunchKernelGGL(attn_fused, dim3(1024), dim3(512), 0, stream, enc, Wbf2, c, v, part);
    hipLaunchKernelGGL(softmax_k,  dim3(32),   dim3(256), 0, stream, part, out, 8);
}